// Round 4
// baseline (383.356 us; speedup 1.0000x reference)
//
#include <hip/hip_runtime.h>
#include <math.h>

#define C     128
#define C2U   64          // uints (2x bf16) per row
#define GEMM_ROWS 16
#define CHUNK 1024        // scan chunk per block (256 threads * 4)

// ---- bf16 helpers (manual RNE; avoids header API differences) ----
__device__ __forceinline__ unsigned int f2bf(float f) {
    unsigned int u = __float_as_uint(f);
    return (u + 0x7fffu + ((u >> 16) & 1u)) >> 16;
}
__device__ __forceinline__ float bflo(unsigned int v) {   // low bf16 of packed pair
    return __uint_as_float(v << 16);
}
__device__ __forceinline__ float bfhi(unsigned int v) {   // high bf16 of packed pair
    return __uint_as_float(v & 0xffff0000u);
}

// ---------------- x fp32 -> packed bf16 ----------------
__global__ __launch_bounds__(256) void ngl_cvt_kernel(const float4* __restrict__ x4,
                                                      uint4* __restrict__ xh4, int n8) {
    int t = blockIdx.x * blockDim.x + threadIdx.x;
    if (t >= n8) return;
    float4 a = x4[2 * t], b = x4[2 * t + 1];
    uint4 o;
    o.x = f2bf(a.x) | (f2bf(a.y) << 16);
    o.y = f2bf(a.z) | (f2bf(a.w) << 16);
    o.z = f2bf(b.x) | (f2bf(b.y) << 16);
    o.w = f2bf(b.z) | (f2bf(b.w) << 16);
    xh4[t] = o;
}

// ---------------- degree ----------------
__global__ void ngl_deg_kernel(const int* __restrict__ dst, int E, int* __restrict__ deg) {
    int e = blockIdx.x * blockDim.x + threadIdx.x;
    if (e < E) atomicAdd(&deg[dst[e]], 1);
}

// scan pass A: per-block sum of deg chunk; fused dis[i] = rsqrt(deg[i]+1)
__global__ __launch_bounds__(256) void ngl_bsum_dis_kernel(
        const int* __restrict__ deg, float* __restrict__ dis,
        int* __restrict__ bsum, int N) {
    __shared__ int red[256];
    int t = threadIdx.x;
    int base = blockIdx.x * CHUNK + t * 4;
    int s = 0;
    #pragma unroll
    for (int j = 0; j < 4; ++j) {
        int i = base + j;
        if (i < N) {
            int dv = deg[i];
            s += dv;
            dis[i] = rsqrtf((float)(dv + 1));
        }
    }
    red[t] = s;
    __syncthreads();
    for (int o = 128; o > 0; o >>= 1) {
        if (t < o) red[t] += red[t + o];
        __syncthreads();
    }
    if (t == 0) bsum[blockIdx.x] = red[0];
}

// scan pass B: single small block, exclusive scan of block sums (NB <= 256)
__global__ __launch_bounds__(256) void ngl_bscan_kernel(int* __restrict__ bsum, int NB) {
    __shared__ int s[256];
    int t = threadIdx.x;
    s[t] = (t < NB) ? bsum[t] : 0;
    __syncthreads();
    for (int o = 1; o < 256; o <<= 1) {
        int v = 0;
        if (t >= o) v = s[t - o];
        __syncthreads();
        if (t >= o) s[t] += v;
        __syncthreads();
    }
    if (t < NB) bsum[t] = (t == 0) ? 0 : s[t - 1];
}

// scan pass C: per-block scan + block offset -> exclusive offset[]
__global__ __launch_bounds__(256) void ngl_offset_kernel(
        const int* __restrict__ deg, const int* __restrict__ boff,
        int* __restrict__ offset, int N) {
    __shared__ int red[256];
    int t = threadIdx.x;
    int base = blockIdx.x * CHUNK + t * 4;
    int v[4];
    int s = 0;
    #pragma unroll
    for (int j = 0; j < 4; ++j) {
        int i = base + j;
        v[j] = (i < N) ? deg[i] : 0;
        s += v[j];
    }
    red[t] = s;
    __syncthreads();
    for (int o = 1; o < 256; o <<= 1) {
        int u = 0;
        if (t >= o) u = red[t - o];
        __syncthreads();
        if (t >= o) red[t] += u;
        __syncthreads();
    }
    int run = boff[blockIdx.x] + ((t == 0) ? 0 : red[t - 1]);
    #pragma unroll
    for (int j = 0; j < 4; ++j) {
        int i = base + j;
        if (i < N) {
            offset[i] = run;
            run += v[j];
        }
    }
}

// counting-sort scatter: payload[pos] = {src, w}
__global__ void ngl_sort_kernel(const int* __restrict__ src, const int* __restrict__ dst, int E,
                                const float* __restrict__ dis, const int* __restrict__ offset,
                                int* __restrict__ cursor, int2* __restrict__ payload) {
    int e = blockIdx.x * blockDim.x + threadIdx.x;
    if (e >= E) return;
    int s = src[e], d = dst[e];
    int pos = offset[d] + atomicAdd(&cursor[d], 1);
    float w = dis[s] * dis[d];
    payload[pos] = make_int2(s, __float_as_int(w));
}

// one wave per node: registers accumulate the 128-wide row (bf16-pair per lane)
__global__ __launch_bounds__(256) void ngl_gather_kernel(
        const unsigned int* __restrict__ xh, const float* __restrict__ dis,
        const int* __restrict__ offset, const int* __restrict__ deg,
        const int2* __restrict__ payload, unsigned int* __restrict__ agg, int N) {
    int node = blockIdx.x * 4 + (threadIdx.x >> 6);
    int lane = threadIdx.x & 63;
    if (node >= N) return;

    float dn = dis[node];
    float w0 = dn * dn;                       // self-loop norm
    unsigned int sv = xh[(long long)node * C2U + lane];
    float accx = w0 * bflo(sv);
    float accy = w0 * bfhi(sv);

    int beg = offset[node];
    int cnt = deg[node];

    int2 p = (cnt > 0) ? payload[beg] : make_int2(0, 0);
    for (int i = 0; i < cnt; ++i) {
        int2 cur = p;
        if (i + 1 < cnt) p = payload[beg + i + 1];   // prefetch next payload
        float w = __int_as_float(cur.y);
        unsigned int v = xh[(long long)cur.x * C2U + lane];
        accx += w * bflo(v);
        accy += w * bfhi(v);
    }
    agg[(long long)node * C2U + lane] = f2bf(accx) | (f2bf(accy) << 16);
}

__device__ __forceinline__ void fma4(float4& a, float s, const float4& w) {
    a.x += s * w.x; a.y += s * w.y; a.z += s * w.z; a.w += s * w.w;
}

__device__ __forceinline__ float silu1(float v) {
    return v / (1.0f + __expf(-v));
}

// out = silu(agg @ W + b), W (fp32) staged in LDS, agg packed bf16
__global__ __launch_bounds__(256) void ngl_gemm_silu_kernel(
        const uint4* __restrict__ agg4, const float4* __restrict__ W4,
        const float4* __restrict__ b4g, float4* __restrict__ out4,
        int N, int tiles_total) {
    __shared__ float4 Wlds[C * 32];                   // 64 KB: W[k][c4]
    __shared__ unsigned int xs[GEMM_ROWS * C2U];      // 4 KB packed bf16
    __shared__ float4 blds[32];

    int tid = threadIdx.x;
    for (int i = tid; i < C * 32; i += 256) Wlds[i] = W4[i];
    if (tid < 32) blds[tid] = b4g[tid];

    int c4 = tid & 31;
    int rp = tid >> 5;

    for (int tile = blockIdx.x; tile < tiles_total; tile += gridDim.x) {
        int row0 = tile * GEMM_ROWS;
        __syncthreads();
        {
            // 16 rows * 16 uint4/row = 256 uint4; thread tid loads #tid
            int r = tid >> 4;
            uint4 v = (row0 + r < N) ? agg4[(long long)row0 * 16 + tid]
                                     : make_uint4(0, 0, 0, 0);
            reinterpret_cast<uint4*>(xs)[tid] = v;
        }
        __syncthreads();

        float4 acc0 = make_float4(0, 0, 0, 0);
        float4 acc1 = make_float4(0, 0, 0, 0);
        const unsigned int* xr0 = &xs[(rp * 2) * C2U];
        const unsigned int* xr1 = &xs[(rp * 2 + 1) * C2U];
        #pragma unroll 8
        for (int k4 = 0; k4 < 32; ++k4) {
            unsigned int ua = xr0[2 * k4], ub = xr0[2 * k4 + 1];
            unsigned int uc = xr1[2 * k4], ud = xr1[2 * k4 + 1];
            float4 xa = make_float4(bflo(ua), bfhi(ua), bflo(ub), bfhi(ub));
            float4 xb = make_float4(bflo(uc), bfhi(uc), bflo(ud), bfhi(ud));
            float4 w0 = Wlds[(k4 * 4 + 0) * 32 + c4];
            float4 w1 = Wlds[(k4 * 4 + 1) * 32 + c4];
            float4 w2 = Wlds[(k4 * 4 + 2) * 32 + c4];
            float4 w3 = Wlds[(k4 * 4 + 3) * 32 + c4];
            fma4(acc0, xa.x, w0); fma4(acc0, xa.y, w1);
            fma4(acc0, xa.z, w2); fma4(acc0, xa.w, w3);
            fma4(acc1, xb.x, w0); fma4(acc1, xb.y, w1);
            fma4(acc1, xb.z, w2); fma4(acc1, xb.w, w3);
        }

        float4 bb = blds[c4];
        int r0 = row0 + rp * 2;
        if (r0 < N) {
            float4 v = acc0;
            v.x = silu1(v.x + bb.x); v.y = silu1(v.y + bb.y);
            v.z = silu1(v.z + bb.z); v.w = silu1(v.w + bb.w);
            out4[(long long)r0 * 32 + c4] = v;
        }
        if (r0 + 1 < N) {
            float4 v = acc1;
            v.x = silu1(v.x + bb.x); v.y = silu1(v.y + bb.y);
            v.z = silu1(v.z + bb.z); v.w = silu1(v.w + bb.w);
            out4[(long long)(r0 + 1) * 32 + c4] = v;
        }
    }
}

extern "C" void kernel_launch(void* const* d_in, const int* in_sizes, int n_in,
                              void* d_out, int out_size, void* d_ws, size_t ws_size,
                              hipStream_t stream) {
    const float* x = (const float*)d_in[0];
    const int*   ei = (const int*)d_in[1];
    const float* W = (const float*)d_in[2];
    const float* b = (const float*)d_in[3];

    int N = in_sizes[0] / C;
    int E = in_sizes[1] / 2;
    const int* src = ei;
    const int* dst = ei + E;

    char* ws = (char*)d_ws;
    size_t off = 0;
    unsigned int* xh = (unsigned int*)(ws + off);  off += (size_t)N * C * 2;  // 25.6 MB
    unsigned int* agg = (unsigned int*)(ws + off); off += (size_t)N * C * 2;  // 25.6 MB
    int2* payload = (int2*)(ws + off);             off += (size_t)E * 8;      // 12.8 MB
    int* deg = (int*)(ws + off);                   off += (size_t)N * 4;
    int* offset = (int*)(ws + off);                off += (size_t)N * 4;
    int* cursor = (int*)(ws + off);                off += (size_t)N * 4;
    float* dis = (float*)(ws + off);               off += (size_t)N * 4;
    int* bsum = (int*)(ws + off);                  off += 1024 * 4;

    int NB = (N + CHUNK - 1) / CHUNK;     // 98 blocks for N=100k (<=256 required)

    hipMemsetAsync(deg, 0, (size_t)N * 4, stream);
    hipMemsetAsync(cursor, 0, (size_t)N * 4, stream);

    int n8 = N * C / 8;
    ngl_cvt_kernel<<<(n8 + 255) / 256, 256, 0, stream>>>(
        (const float4*)x, (uint4*)xh, n8);
    ngl_deg_kernel<<<(E + 255) / 256, 256, 0, stream>>>(dst, E, deg);
    ngl_bsum_dis_kernel<<<NB, 256, 0, stream>>>(deg, dis, bsum, N);
    ngl_bscan_kernel<<<1, 256, 0, stream>>>(bsum, NB);
    ngl_offset_kernel<<<NB, 256, 0, stream>>>(deg, bsum, offset, N);
    ngl_sort_kernel<<<(E + 255) / 256, 256, 0, stream>>>(src, dst, E, dis, offset, cursor, payload);
    ngl_gather_kernel<<<(N + 3) / 4, 256, 0, stream>>>(
        xh, dis, offset, deg, payload, agg, N);

    int tiles = (N + GEMM_ROWS - 1) / GEMM_ROWS;
    int gblocks = tiles < 2048 ? tiles : 2048;
    ngl_gemm_silu_kernel<<<gblocks, 256, 0, stream>>>(
        (const uint4*)agg, (const float4*)W, (const float4*)b, (float4*)d_out, N, tiles);
}

// Round 5
// 300.601 us; speedup vs baseline: 1.2753x; 1.2753x over previous
//
#include <hip/hip_runtime.h>
#include <math.h>

#define C     128
#define C2U   64          // uints (2x bf16) per row
#define CHUNK 1024        // scan chunk per block (256 threads * 4)

typedef __attribute__((ext_vector_type(8))) short bf16x8;   // 8 bf16 = 4 VGPR
typedef __attribute__((ext_vector_type(4))) float f32x4;

union UV { uint4 u; bf16x8 h; };

// ---- bf16 helpers (manual RNE) ----
__device__ __forceinline__ unsigned int f2bf(float f) {
    unsigned int u = __float_as_uint(f);
    return (u + 0x7fffu + ((u >> 16) & 1u)) >> 16;
}
__device__ __forceinline__ float bflo(unsigned int v) { return __uint_as_float(v << 16); }
__device__ __forceinline__ float bfhi(unsigned int v) { return __uint_as_float(v & 0xffff0000u); }

// ---------------- x fp32 -> packed bf16 ----------------
__global__ __launch_bounds__(256) void ngl_cvt_kernel(const float4* __restrict__ x4,
                                                      uint4* __restrict__ xh4, int n8) {
    int t = blockIdx.x * blockDim.x + threadIdx.x;
    if (t >= n8) return;
    float4 a = x4[2 * t], b = x4[2 * t + 1];
    uint4 o;
    o.x = f2bf(a.x) | (f2bf(a.y) << 16);
    o.y = f2bf(a.z) | (f2bf(a.w) << 16);
    o.z = f2bf(b.x) | (f2bf(b.y) << 16);
    o.w = f2bf(b.z) | (f2bf(b.w) << 16);
    xh4[t] = o;
}

// ---------------- W fp32 -> W^T packed bf16 ----------------
// Wt_u32[col*64 + k2] = bf16(W[2k2][col]) | bf16(W[2k2+1][col])<<16
__global__ __launch_bounds__(256) void ngl_wt_kernel(const float* __restrict__ W,
                                                     unsigned int* __restrict__ Wt) {
    int t = blockIdx.x * blockDim.x + threadIdx.x;   // 128*64
    if (t >= C * C2U) return;
    int col = t >> 6, k2 = t & 63;
    float w0 = W[(2 * k2) * C + col];
    float w1 = W[(2 * k2 + 1) * C + col];
    Wt[col * C2U + k2] = f2bf(w0) | (f2bf(w1) << 16);
}

// ---------------- degree ----------------
__global__ void ngl_deg_kernel(const int* __restrict__ dst, int E, int* __restrict__ deg) {
    int e = blockIdx.x * blockDim.x + threadIdx.x;
    if (e < E) atomicAdd(&deg[dst[e]], 1);
}

// scan pass A: per-block sum of deg chunk; fused dis[i] = rsqrt(deg[i]+1)
__global__ __launch_bounds__(256) void ngl_bsum_dis_kernel(
        const int* __restrict__ deg, float* __restrict__ dis,
        int* __restrict__ bsum, int N) {
    __shared__ int red[256];
    int t = threadIdx.x;
    int base = blockIdx.x * CHUNK + t * 4;
    int s = 0;
    #pragma unroll
    for (int j = 0; j < 4; ++j) {
        int i = base + j;
        if (i < N) {
            int dv = deg[i];
            s += dv;
            dis[i] = rsqrtf((float)(dv + 1));
        }
    }
    red[t] = s;
    __syncthreads();
    for (int o = 128; o > 0; o >>= 1) {
        if (t < o) red[t] += red[t + o];
        __syncthreads();
    }
    if (t == 0) bsum[blockIdx.x] = red[0];
}

// scan pass B: exclusive scan of block sums (NB <= 256)
__global__ __launch_bounds__(256) void ngl_bscan_kernel(int* __restrict__ bsum, int NB) {
    __shared__ int s[256];
    int t = threadIdx.x;
    s[t] = (t < NB) ? bsum[t] : 0;
    __syncthreads();
    for (int o = 1; o < 256; o <<= 1) {
        int v = 0;
        if (t >= o) v = s[t - o];
        __syncthreads();
        if (t >= o) s[t] += v;
        __syncthreads();
    }
    if (t < NB) bsum[t] = (t == 0) ? 0 : s[t - 1];
}

// scan pass C: per-block scan + block offset -> exclusive offset[]
__global__ __launch_bounds__(256) void ngl_offset_kernel(
        const int* __restrict__ deg, const int* __restrict__ boff,
        int* __restrict__ offset, int N) {
    __shared__ int red[256];
    int t = threadIdx.x;
    int base = blockIdx.x * CHUNK + t * 4;
    int v[4];
    int s = 0;
    #pragma unroll
    for (int j = 0; j < 4; ++j) {
        int i = base + j;
        v[j] = (i < N) ? deg[i] : 0;
        s += v[j];
    }
    red[t] = s;
    __syncthreads();
    for (int o = 1; o < 256; o <<= 1) {
        int u = 0;
        if (t >= o) u = red[t - o];
        __syncthreads();
        if (t >= o) red[t] += u;
        __syncthreads();
    }
    int run = boff[blockIdx.x] + ((t == 0) ? 0 : red[t - 1]);
    #pragma unroll
    for (int j = 0; j < 4; ++j) {
        int i = base + j;
        if (i < N) {
            offset[i] = run;
            run += v[j];
        }
    }
}

// counting-sort scatter: payload[pos] = {src, w}
__global__ void ngl_sort_kernel(const int* __restrict__ src, const int* __restrict__ dst, int E,
                                const float* __restrict__ dis, const int* __restrict__ offset,
                                int* __restrict__ cursor, int2* __restrict__ payload) {
    int e = blockIdx.x * blockDim.x + threadIdx.x;
    if (e >= E) return;
    int s = src[e], d = dst[e];
    int pos = offset[d] + atomicAdd(&cursor[d], 1);
    float w = dis[s] * dis[d];
    payload[pos] = make_int2(s, __float_as_int(w));
}

// one wave per node: registers accumulate the 128-wide row (bf16-pair per lane)
__global__ __launch_bounds__(256) void ngl_gather_kernel(
        const unsigned int* __restrict__ xh, const float* __restrict__ dis,
        const int* __restrict__ offset, const int* __restrict__ deg,
        const int2* __restrict__ payload, unsigned int* __restrict__ agg, int N) {
    int node = blockIdx.x * 4 + (threadIdx.x >> 6);
    int lane = threadIdx.x & 63;
    if (node >= N) return;

    float dn = dis[node];
    float w0 = dn * dn;                       // self-loop norm
    unsigned int sv = xh[(long long)node * C2U + lane];
    float accx = w0 * bflo(sv);
    float accy = w0 * bfhi(sv);

    int beg = offset[node];
    int cnt = deg[node];

    int2 p = (cnt > 0) ? payload[beg] : make_int2(0, 0);
    for (int i = 0; i < cnt; ++i) {
        int2 cur = p;
        if (i + 1 < cnt) p = payload[beg + i + 1];   // prefetch next payload
        float w = __int_as_float(cur.y);
        unsigned int v = xh[(long long)cur.x * C2U + lane];
        accx += w * bflo(v);
        accy += w * bfhi(v);
    }
    agg[(long long)node * C2U + lane] = f2bf(accx) | (f2bf(accy) << 16);
}

__device__ __forceinline__ float silu1(float v) {
    return v / (1.0f + __expf(-v));
}

// ---------------- MFMA GEMM: out = silu(agg @ W + b) ----------------
// agg: [N][16 uint4] packed bf16 rows. wt4: W^T [128 cols][16 uint4] packed bf16.
// Per wave: one 16-row M-tile x 128 cols. W^T fragments live in registers.
__global__ __launch_bounds__(256, 2) void ngl_mfma_gemm_kernel(
        const uint4* __restrict__ agg4, const uint4* __restrict__ wt4,
        const float* __restrict__ bias, float* __restrict__ out,
        int N, int tiles_total) {
    int wid  = threadIdx.x >> 6;
    int lane = threadIdx.x & 63;
    int r  = lane & 15;       // row-in-tile (A) / col-in-tile (B,D)
    int kg = lane >> 4;       // k-group 0..3 (k = kg*8 .. kg*8+7 within a 32-chunk)

    // B fragments: bfr[nt][kk] holds W[kk*32+kg*8+j][nt*16+r], j=0..7
    bf16x8 bfr[8][4];
    #pragma unroll
    for (int nt = 0; nt < 8; ++nt) {
        #pragma unroll
        for (int kk = 0; kk < 4; ++kk) {
            UV u; u.u = wt4[(nt * 16 + r) * 16 + kk * 4 + kg];
            bfr[nt][kk] = u.h;
        }
    }
    float bv[8];
    #pragma unroll
    for (int nt = 0; nt < 8; ++nt) bv[nt] = bias[nt * 16 + r];

    for (int tile = blockIdx.x * 4 + wid; tile < tiles_total; tile += gridDim.x * 4) {
        int row0 = tile * 16;
        int arow = row0 + r;

        bf16x8 afr[4];
        #pragma unroll
        for (int kk = 0; kk < 4; ++kk) {
            UV u;
            u.u = (arow < N) ? agg4[(long long)arow * 16 + kk * 4 + kg]
                             : make_uint4(0, 0, 0, 0);
            afr[kk] = u.h;
        }

        f32x4 acc[8];
        #pragma unroll
        for (int nt = 0; nt < 8; ++nt) acc[nt] = (f32x4){0.f, 0.f, 0.f, 0.f};

        #pragma unroll
        for (int kk = 0; kk < 4; ++kk) {
            #pragma unroll
            for (int nt = 0; nt < 8; ++nt) {
                acc[nt] = __builtin_amdgcn_mfma_f32_16x16x32_bf16(
                    afr[kk], bfr[nt][kk], acc[nt], 0, 0, 0);
            }
        }

        // D: row = row0 + kg*4 + j, col = nt*16 + r
        #pragma unroll
        for (int nt = 0; nt < 8; ++nt) {
            #pragma unroll
            for (int j = 0; j < 4; ++j) {
                int rr = row0 + kg * 4 + j;
                if (rr < N)
                    out[(long long)rr * C + nt * 16 + r] = silu1(acc[nt][j] + bv[nt]);
            }
        }
    }
}

extern "C" void kernel_launch(void* const* d_in, const int* in_sizes, int n_in,
                              void* d_out, int out_size, void* d_ws, size_t ws_size,
                              hipStream_t stream) {
    const float* x = (const float*)d_in[0];
    const int*   ei = (const int*)d_in[1];
    const float* W = (const float*)d_in[2];
    const float* b = (const float*)d_in[3];

    int N = in_sizes[0] / C;
    int E = in_sizes[1] / 2;
    const int* src = ei;
    const int* dst = ei + E;

    char* ws = (char*)d_ws;
    size_t off = 0;
    unsigned int* xh = (unsigned int*)(ws + off);  off += (size_t)N * C * 2;  // 25.6 MB
    unsigned int* agg = (unsigned int*)(ws + off); off += (size_t)N * C * 2;  // 25.6 MB
    int2* payload = (int2*)(ws + off);             off += (size_t)E * 8;      // 12.8 MB
    int* deg = (int*)(ws + off);                   off += (size_t)N * 4;
    int* offset = (int*)(ws + off);                off += (size_t)N * 4;
    int* cursor = (int*)(ws + off);                off += (size_t)N * 4;
    float* dis = (float*)(ws + off);               off += (size_t)N * 4;
    int* bsum = (int*)(ws + off);                  off += 1024 * 4;
    unsigned int* Wt = (unsigned int*)(ws + off);  off += (size_t)C * C2U * 4;

    int NB = (N + CHUNK - 1) / CHUNK;     // 98 blocks for N=100k (<=256 required)

    hipMemsetAsync(deg, 0, (size_t)N * 4, stream);
    hipMemsetAsync(cursor, 0, (size_t)N * 4, stream);

    int n8 = N * C / 8;
    ngl_cvt_kernel<<<(n8 + 255) / 256, 256, 0, stream>>>(
        (const float4*)x, (uint4*)xh, n8);
    ngl_wt_kernel<<<(C * C2U + 255) / 256, 256, 0, stream>>>(W, Wt);
    ngl_deg_kernel<<<(E + 255) / 256, 256, 0, stream>>>(dst, E, deg);
    ngl_bsum_dis_kernel<<<NB, 256, 0, stream>>>(deg, dis, bsum, N);
    ngl_bscan_kernel<<<1, 256, 0, stream>>>(bsum, NB);
    ngl_offset_kernel<<<NB, 256, 0, stream>>>(deg, bsum, offset, N);
    ngl_sort_kernel<<<(E + 255) / 256, 256, 0, stream>>>(src, dst, E, dis, offset, cursor, payload);
    ngl_gather_kernel<<<(N + 3) / 4, 256, 0, stream>>>(
        xh, dis, offset, deg, payload, agg, N);

    int tiles = (N + 15) / 16;            // 6250
    ngl_mfma_gemm_kernel<<<512, 256, 0, stream>>>(
        (const uint4*)agg, (const uint4*)Wt, b, (float*)d_out, N, tiles);
}

// Round 6
// 254.806 us; speedup vs baseline: 1.5045x; 1.1797x over previous
//
#include <hip/hip_runtime.h>
#include <math.h>

#define C     128
#define C2U   64          // uints (2x bf16) per row
#define CHUNK 1024        // scan chunk per block (256 threads * 4)

typedef __attribute__((ext_vector_type(8))) short bf16x8;   // 8 bf16 = 4 VGPR
typedef __attribute__((ext_vector_type(4))) float f32x4;

union UV { uint4 u; bf16x8 h; };

// ---- bf16 helpers (manual RNE) ----
__device__ __forceinline__ unsigned int f2bf(float f) {
    unsigned int u = __float_as_uint(f);
    return (u + 0x7fffu + ((u >> 16) & 1u)) >> 16;
}
__device__ __forceinline__ float bflo(unsigned int v) { return __uint_as_float(v << 16); }
__device__ __forceinline__ float bfhi(unsigned int v) { return __uint_as_float(v & 0xffff0000u); }

// ---------------- x fp32 -> packed bf16 ----------------
__global__ __launch_bounds__(256) void ngl_cvt_kernel(const float4* __restrict__ x4,
                                                      uint4* __restrict__ xh4, int n8) {
    int t = blockIdx.x * blockDim.x + threadIdx.x;
    if (t >= n8) return;
    float4 a = x4[2 * t], b = x4[2 * t + 1];
    uint4 o;
    o.x = f2bf(a.x) | (f2bf(a.y) << 16);
    o.y = f2bf(a.z) | (f2bf(a.w) << 16);
    o.z = f2bf(b.x) | (f2bf(b.y) << 16);
    o.w = f2bf(b.z) | (f2bf(b.w) << 16);
    xh4[t] = o;
}

// ---------------- W fp32 -> W^T packed bf16 ----------------
__global__ __launch_bounds__(256) void ngl_wt_kernel(const float* __restrict__ W,
                                                     unsigned int* __restrict__ Wt) {
    int t = blockIdx.x * blockDim.x + threadIdx.x;   // 128*64
    if (t >= C * C2U) return;
    int col = t >> 6, k2 = t & 63;
    float w0 = W[(2 * k2) * C + col];
    float w1 = W[(2 * k2 + 1) * C + col];
    Wt[col * C2U + k2] = f2bf(w0) | (f2bf(w1) << 16);
}

// ---------------- degree ----------------
__global__ void ngl_deg_kernel(const int* __restrict__ dst, int E, int* __restrict__ deg) {
    int e = blockIdx.x * blockDim.x + threadIdx.x;
    if (e < E) atomicAdd(&deg[dst[e]], 1);
}

// scan pass A: per-block sum of deg chunk; fused dis[i] = rsqrt(deg[i]+1)
__global__ __launch_bounds__(256) void ngl_bsum_dis_kernel(
        const int* __restrict__ deg, float* __restrict__ dis,
        int* __restrict__ bsum, int N) {
    __shared__ int red[256];
    int t = threadIdx.x;
    int base = blockIdx.x * CHUNK + t * 4;
    int s = 0;
    #pragma unroll
    for (int j = 0; j < 4; ++j) {
        int i = base + j;
        if (i < N) {
            int dv = deg[i];
            s += dv;
            dis[i] = rsqrtf((float)(dv + 1));
        }
    }
    red[t] = s;
    __syncthreads();
    for (int o = 128; o > 0; o >>= 1) {
        if (t < o) red[t] += red[t + o];
        __syncthreads();
    }
    if (t == 0) bsum[blockIdx.x] = red[0];
}

// scan pass B: exclusive scan of block sums (NB <= 256)
__global__ __launch_bounds__(256) void ngl_bscan_kernel(int* __restrict__ bsum, int NB) {
    __shared__ int s[256];
    int t = threadIdx.x;
    s[t] = (t < NB) ? bsum[t] : 0;
    __syncthreads();
    for (int o = 1; o < 256; o <<= 1) {
        int v = 0;
        if (t >= o) v = s[t - o];
        __syncthreads();
        if (t >= o) s[t] += v;
        __syncthreads();
    }
    if (t < NB) bsum[t] = (t == 0) ? 0 : s[t - 1];
}

// scan pass C: per-block scan + block offset -> exclusive offset[]
__global__ __launch_bounds__(256) void ngl_offset_kernel(
        const int* __restrict__ deg, const int* __restrict__ boff,
        int* __restrict__ offset, int N) {
    __shared__ int red[256];
    int t = threadIdx.x;
    int base = blockIdx.x * CHUNK + t * 4;
    int v[4];
    int s = 0;
    #pragma unroll
    for (int j = 0; j < 4; ++j) {
        int i = base + j;
        v[j] = (i < N) ? deg[i] : 0;
        s += v[j];
    }
    red[t] = s;
    __syncthreads();
    for (int o = 1; o < 256; o <<= 1) {
        int u = 0;
        if (t >= o) u = red[t - o];
        __syncthreads();
        if (t >= o) red[t] += u;
        __syncthreads();
    }
    int run = boff[blockIdx.x] + ((t == 0) ? 0 : red[t - 1]);
    #pragma unroll
    for (int j = 0; j < 4; ++j) {
        int i = base + j;
        if (i < N) {
            offset[i] = run;
            run += v[j];
        }
    }
}

// counting-sort scatter: payload[pos] = {src, w}
__global__ void ngl_sort_kernel(const int* __restrict__ src, const int* __restrict__ dst, int E,
                                const float* __restrict__ dis, const int* __restrict__ offset,
                                int* __restrict__ cursor, int2* __restrict__ payload) {
    int e = blockIdx.x * blockDim.x + threadIdx.x;
    if (e >= E) return;
    int s = src[e], d = dst[e];
    int pos = offset[d] + atomicAdd(&cursor[d], 1);
    float w = dis[s] * dis[d];
    payload[pos] = make_int2(s, __float_as_int(w));
}

// one wave per node; 4x unrolled edge loop with payload double-buffer so
// 4 random 256B x-row loads are in flight per wave (latency -> MLP).
__global__ __launch_bounds__(256) void ngl_gather_kernel(
        const unsigned int* __restrict__ xh, const float* __restrict__ dis,
        const int* __restrict__ offset, const int* __restrict__ deg,
        const int2* __restrict__ payload, unsigned int* __restrict__ agg, int N) {
    int node = blockIdx.x * 4 + (threadIdx.x >> 6);
    int lane = threadIdx.x & 63;
    if (node >= N) return;

    float dn = dis[node];
    float w0 = dn * dn;                       // self-loop norm
    unsigned int sv = xh[(long long)node * C2U + lane];
    float accx = w0 * bflo(sv);
    float accy = w0 * bfhi(sv);

    int beg = offset[node];
    int cnt = deg[node];

    int2 e0, e1, e2, e3;
    int i = 0;
    if (cnt >= 4) {
        e0 = payload[beg + 0]; e1 = payload[beg + 1];
        e2 = payload[beg + 2]; e3 = payload[beg + 3];
        while (i + 4 <= cnt) {
            int2 c0 = e0, c1 = e1, c2 = e2, c3 = e3;
            int nb = beg + i + 4;
            if (i + 8 <= cnt) {                 // prefetch next payload group
                e0 = payload[nb + 0]; e1 = payload[nb + 1];
                e2 = payload[nb + 2]; e3 = payload[nb + 3];
            }
            unsigned int v0 = xh[(long long)c0.x * C2U + lane];
            unsigned int v1 = xh[(long long)c1.x * C2U + lane];
            unsigned int v2 = xh[(long long)c2.x * C2U + lane];
            unsigned int v3 = xh[(long long)c3.x * C2U + lane];
            float f0 = __int_as_float(c0.y), f1 = __int_as_float(c1.y);
            float f2 = __int_as_float(c2.y), f3 = __int_as_float(c3.y);
            accx += f0 * bflo(v0); accy += f0 * bfhi(v0);
            accx += f1 * bflo(v1); accy += f1 * bfhi(v1);
            accx += f2 * bflo(v2); accy += f2 * bfhi(v2);
            accx += f3 * bflo(v3); accy += f3 * bfhi(v3);
            i += 4;
        }
    }
    for (; i < cnt; ++i) {
        int2 cur = payload[beg + i];
        float w = __int_as_float(cur.y);
        unsigned int v = xh[(long long)cur.x * C2U + lane];
        accx += w * bflo(v);
        accy += w * bfhi(v);
    }
    agg[(long long)node * C2U + lane] = f2bf(accx) | (f2bf(accy) << 16);
}

__device__ __forceinline__ float silu1(float v) {
    return v / (1.0f + __expf(-v));
}

// ---------------- MFMA GEMM: out = silu(agg @ W + b) ----------------
__global__ __launch_bounds__(256, 2) void ngl_mfma_gemm_kernel(
        const uint4* __restrict__ agg4, const uint4* __restrict__ wt4,
        const float* __restrict__ bias, float* __restrict__ out,
        int N, int tiles_total) {
    int wid  = threadIdx.x >> 6;
    int lane = threadIdx.x & 63;
    int r  = lane & 15;       // row-in-tile (A) / col-in-tile (B,D)
    int kg = lane >> 4;       // k-group 0..3

    bf16x8 bfr[8][4];
    #pragma unroll
    for (int nt = 0; nt < 8; ++nt) {
        #pragma unroll
        for (int kk = 0; kk < 4; ++kk) {
            UV u; u.u = wt4[(nt * 16 + r) * 16 + kk * 4 + kg];
            bfr[nt][kk] = u.h;
        }
    }
    float bv[8];
    #pragma unroll
    for (int nt = 0; nt < 8; ++nt) bv[nt] = bias[nt * 16 + r];

    for (int tile = blockIdx.x * 4 + wid; tile < tiles_total; tile += gridDim.x * 4) {
        int row0 = tile * 16;
        int arow = row0 + r;

        bf16x8 afr[4];
        #pragma unroll
        for (int kk = 0; kk < 4; ++kk) {
            UV u;
            u.u = (arow < N) ? agg4[(long long)arow * 16 + kk * 4 + kg]
                             : make_uint4(0, 0, 0, 0);
            afr[kk] = u.h;
        }

        f32x4 acc[8];
        #pragma unroll
        for (int nt = 0; nt < 8; ++nt) acc[nt] = (f32x4){0.f, 0.f, 0.f, 0.f};

        #pragma unroll
        for (int kk = 0; kk < 4; ++kk) {
            #pragma unroll
            for (int nt = 0; nt < 8; ++nt) {
                acc[nt] = __builtin_amdgcn_mfma_f32_16x16x32_bf16(
                    afr[kk], bfr[nt][kk], acc[nt], 0, 0, 0);
            }
        }

        #pragma unroll
        for (int nt = 0; nt < 8; ++nt) {
            #pragma unroll
            for (int j = 0; j < 4; ++j) {
                int rr = row0 + kg * 4 + j;
                if (rr < N)
                    out[(long long)rr * C + nt * 16 + r] = silu1(acc[nt][j] + bv[nt]);
            }
        }
    }
}

extern "C" void kernel_launch(void* const* d_in, const int* in_sizes, int n_in,
                              void* d_out, int out_size, void* d_ws, size_t ws_size,
                              hipStream_t stream) {
    const float* x = (const float*)d_in[0];
    const int*   ei = (const int*)d_in[1];
    const float* W = (const float*)d_in[2];
    const float* b = (const float*)d_in[3];

    int N = in_sizes[0] / C;
    int E = in_sizes[1] / 2;
    const int* src = ei;
    const int* dst = ei + E;

    char* ws = (char*)d_ws;
    size_t off = 0;
    unsigned int* xh = (unsigned int*)(ws + off);  off += (size_t)N * C * 2;  // 25.6 MB
    unsigned int* agg = (unsigned int*)(ws + off); off += (size_t)N * C * 2;  // 25.6 MB
    int2* payload = (int2*)(ws + off);             off += (size_t)E * 8;      // 12.8 MB
    int* deg = (int*)(ws + off);                   off += (size_t)N * 4;
    int* offset = (int*)(ws + off);                off += (size_t)N * 4;
    int* cursor = (int*)(ws + off);                off += (size_t)N * 4;
    float* dis = (float*)(ws + off);               off += (size_t)N * 4;
    int* bsum = (int*)(ws + off);                  off += 1024 * 4;
    unsigned int* Wt = (unsigned int*)(ws + off);  off += (size_t)C * C2U * 4;

    int NB = (N + CHUNK - 1) / CHUNK;     // 98 blocks for N=100k (<=256 required)

    hipMemsetAsync(deg, 0, (size_t)N * 4, stream);
    hipMemsetAsync(cursor, 0, (size_t)N * 4, stream);

    int n8 = N * C / 8;
    ngl_cvt_kernel<<<(n8 + 255) / 256, 256, 0, stream>>>(
        (const float4*)x, (uint4*)xh, n8);
    ngl_wt_kernel<<<(C * C2U + 255) / 256, 256, 0, stream>>>(W, Wt);
    ngl_deg_kernel<<<(E + 255) / 256, 256, 0, stream>>>(dst, E, deg);
    ngl_bsum_dis_kernel<<<NB, 256, 0, stream>>>(deg, dis, bsum, N);
    ngl_bscan_kernel<<<1, 256, 0, stream>>>(bsum, NB);
    ngl_offset_kernel<<<NB, 256, 0, stream>>>(deg, bsum, offset, N);
    ngl_sort_kernel<<<(E + 255) / 256, 256, 0, stream>>>(src, dst, E, dis, offset, cursor, payload);
    ngl_gather_kernel<<<(N + 3) / 4, 256, 0, stream>>>(
        xh, dis, offset, deg, payload, agg, N);

    int tiles = (N + 15) / 16;            // 6250
    ngl_mfma_gemm_kernel<<<512, 256, 0, stream>>>(
        (const uint4*)agg, (const uint4*)Wt, b, (float*)d_out, N, tiles);
}

// Round 8
// 248.606 us; speedup vs baseline: 1.5420x; 1.0249x over previous
//
#include <hip/hip_runtime.h>
#include <math.h>

#define C     128
#define C2U   64          // uints (2x bf16) per row
#define CHUNK 1024        // scan chunk per block (256 threads * 4)

typedef __attribute__((ext_vector_type(8))) short bf16x8;   // 8 bf16 = 4 VGPR
typedef __attribute__((ext_vector_type(4))) float f32x4;

union UV { uint4 u; bf16x8 h; };

// ---- bf16 helpers (manual RNE) ----
__device__ __forceinline__ unsigned int f2bf(float f) {
    unsigned int u = __float_as_uint(f);
    return (u + 0x7fffu + ((u >> 16) & 1u)) >> 16;
}
__device__ __forceinline__ float bflo(unsigned int v) { return __uint_as_float(v << 16); }
__device__ __forceinline__ float bfhi(unsigned int v) { return __uint_as_float(v & 0xffff0000u); }

// ---------------- x fp32 -> packed bf16 ----------------
__global__ __launch_bounds__(256) void ngl_cvt_kernel(const float4* __restrict__ x4,
                                                      uint4* __restrict__ xh4, int n8) {
    int t = blockIdx.x * blockDim.x + threadIdx.x;
    if (t >= n8) return;
    float4 a = x4[2 * t], b = x4[2 * t + 1];
    uint4 o;
    o.x = f2bf(a.x) | (f2bf(a.y) << 16);
    o.y = f2bf(a.z) | (f2bf(a.w) << 16);
    o.z = f2bf(b.x) | (f2bf(b.y) << 16);
    o.w = f2bf(b.z) | (f2bf(b.w) << 16);
    xh4[t] = o;
}

// ---------------- W fp32 -> W^T packed bf16 ----------------
__global__ __launch_bounds__(256) void ngl_wt_kernel(const float* __restrict__ W,
                                                     unsigned int* __restrict__ Wt) {
    int t = blockIdx.x * blockDim.x + threadIdx.x;   // 128*64
    if (t >= C * C2U) return;
    int col = t >> 6, k2 = t & 63;
    float w0 = W[(2 * k2) * C + col];
    float w1 = W[(2 * k2 + 1) * C + col];
    Wt[col * C2U + k2] = f2bf(w0) | (f2bf(w1) << 16);
}

// ---------------- degree + slot (fused counting-sort rank) ----------------
__global__ void ngl_deg_kernel(const int* __restrict__ dst, int E,
                               int* __restrict__ deg, int* __restrict__ slot) {
    int e = blockIdx.x * blockDim.x + threadIdx.x;
    if (e < E) slot[e] = atomicAdd(&deg[dst[e]], 1);
}

// scan pass A: per-block sum of deg chunk; fused dis[i] = rsqrt(deg[i]+1)
__global__ __launch_bounds__(256) void ngl_bsum_dis_kernel(
        const int* __restrict__ deg, float* __restrict__ dis,
        int* __restrict__ bsum, int N) {
    __shared__ int red[256];
    int t = threadIdx.x;
    int base = blockIdx.x * CHUNK + t * 4;
    int s = 0;
    #pragma unroll
    for (int j = 0; j < 4; ++j) {
        int i = base + j;
        if (i < N) {
            int dv = deg[i];
            s += dv;
            dis[i] = rsqrtf((float)(dv + 1));
        }
    }
    red[t] = s;
    __syncthreads();
    for (int o = 128; o > 0; o >>= 1) {
        if (t < o) red[t] += red[t + o];
        __syncthreads();
    }
    if (t == 0) bsum[blockIdx.x] = red[0];
}

// scan pass B: exclusive scan of block sums (NB <= 256)
__global__ __launch_bounds__(256) void ngl_bscan_kernel(int* __restrict__ bsum, int NB) {
    __shared__ int s[256];
    int t = threadIdx.x;
    s[t] = (t < NB) ? bsum[t] : 0;
    __syncthreads();
    for (int o = 1; o < 256; o <<= 1) {
        int v = 0;
        if (t >= o) v = s[t - o];
        __syncthreads();
        if (t >= o) s[t] += v;
        __syncthreads();
    }
    if (t < NB) bsum[t] = (t == 0) ? 0 : s[t - 1];
}

// scan pass C: per-block scan + block offset -> exclusive offset[]
__global__ __launch_bounds__(256) void ngl_offset_kernel(
        const int* __restrict__ deg, const int* __restrict__ boff,
        int* __restrict__ offset, int N) {
    __shared__ int red[256];
    int t = threadIdx.x;
    int base = blockIdx.x * CHUNK + t * 4;
    int v[4];
    int s = 0;
    #pragma unroll
    for (int j = 0; j < 4; ++j) {
        int i = base + j;
        v[j] = (i < N) ? deg[i] : 0;
        s += v[j];
    }
    red[t] = s;
    __syncthreads();
    for (int o = 1; o < 256; o <<= 1) {
        int u = 0;
        if (t >= o) u = red[t - o];
        __syncthreads();
        if (t >= o) red[t] += u;
        __syncthreads();
    }
    int run = boff[blockIdx.x] + ((t == 0) ? 0 : red[t - 1]);
    #pragma unroll
    for (int j = 0; j < 4; ++j) {
        int i = base + j;
        if (i < N) {
            offset[i] = run;
            run += v[j];
        }
    }
}

// counting-sort scatter (atomic-free): payload[offset[d]+slot[e]] = {src, w}
// packed as u64 (low = src, high = w bits) for the nontemporal builtin.
__global__ void ngl_sort_kernel(const int* __restrict__ src, const int* __restrict__ dst, int E,
                                const float* __restrict__ dis, const int* __restrict__ offset,
                                const int* __restrict__ slot,
                                unsigned long long* __restrict__ payload) {
    int e = blockIdx.x * blockDim.x + threadIdx.x;
    if (e >= E) return;
    int s = src[e], d = dst[e];
    int pos = offset[d] + slot[e];
    float w = dis[s] * dis[d];
    unsigned long long pk = (unsigned long long)(unsigned int)s |
                            ((unsigned long long)(unsigned int)__float_as_uint(w) << 32);
    __builtin_nontemporal_store(pk, &payload[pos]);
}

// one wave per node; 8-deep software pipeline: 8 payload entries + 8 random
// 256B x-row loads in flight per wave (MLP against L2/L3 latency).
__global__ __launch_bounds__(256) void ngl_gather_kernel(
        const unsigned int* __restrict__ xh, const float* __restrict__ dis,
        const int* __restrict__ offset, const int* __restrict__ deg,
        const int2* __restrict__ payload, unsigned int* __restrict__ agg, int N) {
    int node = blockIdx.x * 4 + (threadIdx.x >> 6);
    int lane = threadIdx.x & 63;
    if (node >= N) return;

    float dn = dis[node];
    float w0 = dn * dn;                       // self-loop norm
    unsigned int sv = xh[(long long)node * C2U + lane];
    float accx = w0 * bflo(sv);
    float accy = w0 * bfhi(sv);

    int beg = offset[node];
    int cnt = deg[node];

    int2 e[8];
    int i = 0;
    if (cnt >= 8) {
        #pragma unroll
        for (int j = 0; j < 8; ++j) e[j] = payload[beg + j];
        while (i + 8 <= cnt) {
            int2 c[8];
            #pragma unroll
            for (int j = 0; j < 8; ++j) c[j] = e[j];
            if (i + 16 <= cnt) {
                #pragma unroll
                for (int j = 0; j < 8; ++j) e[j] = payload[beg + i + 8 + j];
            }
            unsigned int v[8];
            #pragma unroll
            for (int j = 0; j < 8; ++j)
                v[j] = xh[(long long)c[j].x * C2U + lane];
            #pragma unroll
            for (int j = 0; j < 8; ++j) {
                float f = __int_as_float(c[j].y);
                accx += f * bflo(v[j]);
                accy += f * bfhi(v[j]);
            }
            i += 8;
        }
    }
    for (; i < cnt; ++i) {
        int2 cur = payload[beg + i];
        float w = __int_as_float(cur.y);
        unsigned int v = xh[(long long)cur.x * C2U + lane];
        accx += w * bflo(v);
        accy += w * bfhi(v);
    }
    agg[(long long)node * C2U + lane] = f2bf(accx) | (f2bf(accy) << 16);
}

__device__ __forceinline__ float silu1(float v) {
    return v / (1.0f + __expf(-v));
}

// ---------------- MFMA GEMM: out = silu(agg @ W + b) ----------------
__global__ __launch_bounds__(256, 2) void ngl_mfma_gemm_kernel(
        const uint4* __restrict__ agg4, const uint4* __restrict__ wt4,
        const float* __restrict__ bias, float* __restrict__ out,
        int N, int tiles_total) {
    int wid  = threadIdx.x >> 6;
    int lane = threadIdx.x & 63;
    int r  = lane & 15;       // row-in-tile (A) / col-in-tile (B,D)
    int kg = lane >> 4;       // k-group 0..3

    bf16x8 bfr[8][4];
    #pragma unroll
    for (int nt = 0; nt < 8; ++nt) {
        #pragma unroll
        for (int kk = 0; kk < 4; ++kk) {
            UV u; u.u = wt4[(nt * 16 + r) * 16 + kk * 4 + kg];
            bfr[nt][kk] = u.h;
        }
    }
    float bv[8];
    #pragma unroll
    for (int nt = 0; nt < 8; ++nt) bv[nt] = bias[nt * 16 + r];

    for (int tile = blockIdx.x * 4 + wid; tile < tiles_total; tile += gridDim.x * 4) {
        int row0 = tile * 16;
        int arow = row0 + r;

        bf16x8 afr[4];
        #pragma unroll
        for (int kk = 0; kk < 4; ++kk) {
            UV u;
            u.u = (arow < N) ? agg4[(long long)arow * 16 + kk * 4 + kg]
                             : make_uint4(0, 0, 0, 0);
            afr[kk] = u.h;
        }

        f32x4 acc[8];
        #pragma unroll
        for (int nt = 0; nt < 8; ++nt) acc[nt] = (f32x4){0.f, 0.f, 0.f, 0.f};

        #pragma unroll
        for (int kk = 0; kk < 4; ++kk) {
            #pragma unroll
            for (int nt = 0; nt < 8; ++nt) {
                acc[nt] = __builtin_amdgcn_mfma_f32_16x16x32_bf16(
                    afr[kk], bfr[nt][kk], acc[nt], 0, 0, 0);
            }
        }

        #pragma unroll
        for (int nt = 0; nt < 8; ++nt) {
            #pragma unroll
            for (int j = 0; j < 4; ++j) {
                int rr = row0 + kg * 4 + j;
                if (rr < N)
                    __builtin_nontemporal_store(
                        silu1(acc[nt][j] + bv[nt]),
                        &out[(long long)rr * C + nt * 16 + r]);
            }
        }
    }
}

extern "C" void kernel_launch(void* const* d_in, const int* in_sizes, int n_in,
                              void* d_out, int out_size, void* d_ws, size_t ws_size,
                              hipStream_t stream) {
    const float* x = (const float*)d_in[0];
    const int*   ei = (const int*)d_in[1];
    const float* W = (const float*)d_in[2];
    const float* b = (const float*)d_in[3];

    int N = in_sizes[0] / C;
    int E = in_sizes[1] / 2;
    const int* src = ei;
    const int* dst = ei + E;

    char* ws = (char*)d_ws;
    size_t off = 0;
    unsigned int* xh = (unsigned int*)(ws + off);  off += (size_t)N * C * 2;  // 25.6 MB
    unsigned int* agg = (unsigned int*)(ws + off); off += (size_t)N * C * 2;  // 25.6 MB
    unsigned long long* payload = (unsigned long long*)(ws + off); off += (size_t)E * 8; // 12.8 MB
    int* slot = (int*)(ws + off);                  off += (size_t)E * 4;      // 6.4 MB
    int* deg = (int*)(ws + off);                   off += (size_t)N * 4;
    int* offset = (int*)(ws + off);                off += (size_t)N * 4;
    float* dis = (float*)(ws + off);               off += (size_t)N * 4;
    int* bsum = (int*)(ws + off);                  off += 1024 * 4;
    unsigned int* Wt = (unsigned int*)(ws + off);  off += (size_t)C * C2U * 4;

    int NB = (N + CHUNK - 1) / CHUNK;     // 98 blocks for N=100k (<=256 required)

    (void)hipMemsetAsync(deg, 0, (size_t)N * 4, stream);

    int n8 = N * C / 8;
    ngl_cvt_kernel<<<(n8 + 255) / 256, 256, 0, stream>>>(
        (const float4*)x, (uint4*)xh, n8);
    ngl_wt_kernel<<<(C * C2U + 255) / 256, 256, 0, stream>>>(W, Wt);
    ngl_deg_kernel<<<(E + 255) / 256, 256, 0, stream>>>(dst, E, deg, slot);
    ngl_bsum_dis_kernel<<<NB, 256, 0, stream>>>(deg, dis, bsum, N);
    ngl_bscan_kernel<<<1, 256, 0, stream>>>(bsum, NB);
    ngl_offset_kernel<<<NB, 256, 0, stream>>>(deg, bsum, offset, N);
    ngl_sort_kernel<<<(E + 255) / 256, 256, 0, stream>>>(src, dst, E, dis, offset, slot, payload);
    ngl_gather_kernel<<<(N + 3) / 4, 256, 0, stream>>>(
        xh, dis, offset, deg, (const int2*)payload, agg, N);

    int tiles = (N + 15) / 16;            // 6250
    ngl_mfma_gemm_kernel<<<512, 256, 0, stream>>>(
        (const uint4*)agg, (const uint4*)Wt, b, (float*)d_out, N, tiles);
}